// Round 2
// baseline (7737.825 us; speedup 1.0000x reference)
//
#include <hip/hip_runtime.h>

#define U_NUM   100000
#define I_NUM   50000
#define FCT     64
#define NEDGE   3200000
#define BATCH   16384
#define TOTSLOTS (2 * NEDGE)         // 6400000

#define BRU_SHIFT 7                  // 128 user rows per bucket
#define BRI_SHIFT 6                  // 64 item rows per bucket
#define NBU 782                      // ceil(100000/128)
#define NBI 782                      // ceil(50000/64)
#define NBUCK (NBU + NBI)            // 1564
#define CPAD 16                      // pad atomic counters to separate lines

__device__ __forceinline__ unsigned short f2b(float f) {
    unsigned int x = __float_as_uint(f);
    unsigned int r = (x + 0x7FFFu + ((x >> 16) & 1u)) >> 16;   // round-to-nearest-even
    return (unsigned short)r;
}
__device__ __forceinline__ float b2f(unsigned short u) {
    return __uint_as_float(((unsigned int)u) << 16);
}

// ---------------- fp32 -> bf16 table conversion ----------------
__global__ void conv_kernel(const float* __restrict__ in, unsigned short* __restrict__ out, int n4) {
    int t = blockIdx.x * blockDim.x + threadIdx.x;
    if (t >= n4) return;
    float4 v = *reinterpret_cast<const float4*>(in + (size_t)t * 4);
    ushort4 o;
    o.x = f2b(v.x); o.y = f2b(v.y); o.z = f2b(v.z); o.w = f2b(v.w);
    *reinterpret_cast<ushort4*>(out + (size_t)t * 4) = o;
}

// ---------------- bucket histogram ----------------
__global__ void bhist_kernel(const int* __restrict__ eu, const int* __restrict__ ei,
                             int* __restrict__ bcnt) {
    int t = blockIdx.x * blockDim.x + threadIdx.x;
    if (t >= NEDGE) return;
    int bu = eu[t] >> BRU_SHIFT;
    int bi = NBU + (ei[t] >> BRI_SHIFT);
    atomicAdd(&bcnt[bu * CPAD], 1);
    atomicAdd(&bcnt[bi * CPAD], 1);
}

// ---------------- single-block exclusive scan over NBUCK buckets ----------------
__global__ void bscan_kernel(const int* __restrict__ bcnt, int* __restrict__ bbase) {
    __shared__ int s[256];
    int t = threadIdx.x;
    int v[8];
    int tot = 0;
#pragma unroll
    for (int k = 0; k < 8; k++) {
        int idx = t * 8 + k;
        v[k] = (idx < NBUCK) ? bcnt[idx * CPAD] : 0;
        tot += v[k];
    }
    s[t] = tot;
    __syncthreads();
    for (int off = 1; off < 256; off <<= 1) {
        int x = (t >= off) ? s[t - off] : 0;
        __syncthreads();
        s[t] += x;
        __syncthreads();
    }
    int p = s[t] - tot;  // exclusive prefix for this thread's chunk
#pragma unroll
    for (int k = 0; k < 8; k++) {
        int idx = t * 8 + k;
        if (idx < NBUCK) bbase[idx] = p;
        p += v[k];
    }
    if (t == 255) bbase[NBUCK] = s[255];
}

// ---------------- scatter edges into bucket regions (dense appends) ----------------
__global__ void bscatter_kernel(const int* __restrict__ eu, const int* __restrict__ ei,
                                const float* __restrict__ vui, const float* __restrict__ viu,
                                const int* __restrict__ bbase, int* __restrict__ bfill,
                                int2* __restrict__ csr) {
    int t = blockIdx.x * blockDim.x + threadIdx.x;
    if (t >= NEDGE) return;
    int u = eu[t], i = ei[t];
    // user-destination edge: src = item, val = vui
    int bu = u >> BRU_SHIFT;
    int offu = u & ((1 << BRU_SHIFT) - 1);
    int slot = bbase[bu] + atomicAdd(&bfill[bu * CPAD], 1);
    csr[slot] = make_int2((offu << 17) | i, __float_as_int(vui[t]));
    // item-destination edge: src = user, val = viu
    int bi = NBU + (i >> BRI_SHIFT);
    int offi = i & ((1 << BRI_SHIFT) - 1);
    slot = bbase[bi] + atomicAdd(&bfill[bi * CPAD], 1);
    csr[slot] = make_int2((offi << 17) | u, __float_as_int(viu[t]));
}

// ---------------- propagation stage: WG per bucket, LDS fp32 accumulator ----------------
__global__ void __launch_bounds__(256) agg_kernel(
        const unsigned short* __restrict__ uprev, const unsigned short* __restrict__ iprev,
        unsigned short* __restrict__ unext, unsigned short* __restrict__ inext,
        const float* __restrict__ di, const float* __restrict__ dj,
        const int* __restrict__ bbase, const int2* __restrict__ csr) {
    __shared__ float acc[128 * 64];   // 32 KiB
    int b = blockIdx.x;
    int rows, rowBase;
    const unsigned short* selfT;
    const unsigned short* srcT;
    unsigned short* dstT;
    const float* dvec;
    if (b < NBU) {
        rowBase = b << BRU_SHIFT;
        rows = min(128, U_NUM - rowBase);
        selfT = uprev; srcT = iprev; dstT = unext; dvec = di;
    } else {
        int bb = b - NBU;
        rowBase = bb << BRI_SHIFT;
        rows = min(64, I_NUM - rowBase);
        selfT = iprev; srcT = uprev; dstT = inext; dvec = dj;
    }
    int lane = threadIdx.x & 63;
    int wv = threadIdx.x >> 6;

    // init accumulator with the self term prev*d
    for (int r = wv; r < rows; r += 4)
        acc[r * 64 + lane] = b2f(selfT[(size_t)(rowBase + r) * FCT + lane]) * dvec[rowBase + r];
    __syncthreads();

    int beg = bbase[b], end = bbase[b + 1];
    int n = end - beg;
    int per = (n + 3) >> 2;
    int e = beg + wv * per;
    int e1 = min(e + per, end);

    for (; e + 4 <= e1; e += 4) {
        int2 p0 = csr[e], p1 = csr[e + 1], p2 = csr[e + 2], p3 = csr[e + 3];
        int o0 = p0.x >> 17, s0 = p0.x & 0x1FFFF;
        int o1 = p1.x >> 17, s1 = p1.x & 0x1FFFF;
        int o2 = p2.x >> 17, s2 = p2.x & 0x1FFFF;
        int o3 = p3.x >> 17, s3 = p3.x & 0x1FFFF;
        float g0 = b2f(srcT[(size_t)s0 * FCT + lane]);
        float g1 = b2f(srcT[(size_t)s1 * FCT + lane]);
        float g2 = b2f(srcT[(size_t)s2 * FCT + lane]);
        float g3 = b2f(srcT[(size_t)s3 * FCT + lane]);
        atomicAdd(&acc[o0 * 64 + lane], __int_as_float(p0.y) * g0);
        atomicAdd(&acc[o1 * 64 + lane], __int_as_float(p1.y) * g1);
        atomicAdd(&acc[o2 * 64 + lane], __int_as_float(p2.y) * g2);
        atomicAdd(&acc[o3 * 64 + lane], __int_as_float(p3.y) * g3);
    }
    for (; e < e1; ++e) {
        int2 p = csr[e];
        int o = p.x >> 17, s = p.x & 0x1FFFF;
        float g = b2f(srcT[(size_t)s * FCT + lane]);
        atomicAdd(&acc[o * 64 + lane], __int_as_float(p.y) * g);
    }
    __syncthreads();

    // coalesced writeback, fp32 -> bf16
    int total = rows * 64;
    for (int k = threadIdx.x; k < total; k += 256)
        dstT[(size_t)rowBase * FCT + k] = f2b(acc[k]);
}

// ---------------- BPR head ----------------
__global__ void __launch_bounds__(256) batch_kernel(
        const float* __restrict__ u0f, const float* __restrict__ i0f,
        const unsigned short* __restrict__ u1, const unsigned short* __restrict__ u2,
        const unsigned short* __restrict__ u3,
        const unsigned short* __restrict__ i1, const unsigned short* __restrict__ i2,
        const unsigned short* __restrict__ i3,
        const int* __restrict__ user, const int* __restrict__ ita, const int* __restrict__ itb,
        float* __restrict__ out, float* __restrict__ ls, float* __restrict__ l2a) {
    int wid = (blockIdx.x * 256 + threadIdx.x) >> 6;
    int lane = threadIdx.x & 63;
    if (wid >= BATCH) return;
    size_t uo = (size_t)user[wid] * FCT + lane;
    size_t ao = (size_t)ita[wid] * FCT + lane;
    size_t bo = (size_t)itb[wid] * FCT + lane;

    float pi, pj, l2;
    {   // level 0 from exact fp32 inputs
        float ue = u0f[uo], ie = i0f[ao], je = i0f[bo];
        pi = ue * ie; pj = ue * je; l2 = ue * ue + ie * ie + je * je;
    }
    const unsigned short* Ut[3] = {u1, u2, u3};
    const unsigned short* It[3] = {i1, i2, i3};
#pragma unroll
    for (int l = 0; l < 3; l++) {
        float ue = b2f(Ut[l][uo]), ie = b2f(It[l][ao]), je = b2f(It[l][bo]);
        pi += ue * ie;
        pj += ue * je;
        l2 += ue * ue + ie * ie + je * je;
    }
#pragma unroll
    for (int off = 32; off; off >>= 1) {
        pi += __shfl_xor(pi, off);
        pj += __shfl_xor(pj, off);
        l2 += __shfl_xor(l2, off);
    }
    if (lane == 0) {
        out[wid] = pi;
        out[BATCH + wid] = pj;
        float x = pi - pj;
        ls[wid] = fminf(x, 0.0f) - log1pf(expf(-fabsf(x)));  // stable log_sigmoid
        l2a[wid] = 0.01f * l2;
    }
}

__global__ void final_kernel(const float* __restrict__ ls, const float* __restrict__ l2a,
                             float* __restrict__ out) {
    __shared__ float s1[256], s2[256];
    int t = threadIdx.x;
    float a = 0.f, b = 0.f;
    for (int i = t; i < BATCH; i += 256) {
        a += ls[i];
        b += l2a[i];
    }
    s1[t] = a;
    s2[t] = b;
    __syncthreads();
    for (int off = 128; off; off >>= 1) {
        if (t < off) {
            s1[t] += s1[t + off];
            s2[t] += s2[t + off];
        }
        __syncthreads();
    }
    if (t == 0) {
        float loss2 = -s1[0] / (float)BATCH;
        float l2m = s2[0] / (float)BATCH;
        out[2 * BATCH] = loss2 + l2m;      // loss
        out[2 * BATCH + 1] = loss2;        // loss2
    }
}

// ---------------- launch ----------------
extern "C" void kernel_launch(void* const* d_in, const int* in_sizes, int n_in,
                              void* d_out, int out_size, void* d_ws, size_t ws_size,
                              hipStream_t stream) {
    const float* u0f = (const float*)d_in[0];
    const float* i0f = (const float*)d_in[1];
    const float* di  = (const float*)d_in[2];
    const float* dj  = (const float*)d_in[3];
    const float* vui = (const float*)d_in[4];
    const float* viu = (const float*)d_in[5];
    const int*   eu  = (const int*)d_in[6];
    const int*   ei  = (const int*)d_in[7];
    const int*   usr = (const int*)d_in[8];
    const int*   ita = (const int*)d_in[9];
    const int*   itb = (const int*)d_in[10];
    float* out = (float*)d_out;

    char* p = (char*)d_ws;
    auto alloc = [&](size_t bytes) -> char* {
        char* r = p;
        p += (bytes + 255) & ~(size_t)255;
        return r;
    };
    unsigned short* u0b = (unsigned short*)alloc((size_t)U_NUM * FCT * 2);
    unsigned short* u1b = (unsigned short*)alloc((size_t)U_NUM * FCT * 2);
    unsigned short* u2b = (unsigned short*)alloc((size_t)U_NUM * FCT * 2);
    unsigned short* u3b = (unsigned short*)alloc((size_t)U_NUM * FCT * 2);
    unsigned short* i0b = (unsigned short*)alloc((size_t)I_NUM * FCT * 2);
    unsigned short* i1b = (unsigned short*)alloc((size_t)I_NUM * FCT * 2);
    unsigned short* i2b = (unsigned short*)alloc((size_t)I_NUM * FCT * 2);
    unsigned short* i3b = (unsigned short*)alloc((size_t)I_NUM * FCT * 2);
    int2* csr   = (int2*)alloc((size_t)TOTSLOTS * 8);
    int* bcnt   = (int*)alloc((size_t)NBUCK * CPAD * 4);
    int* bfill  = (int*)alloc((size_t)NBUCK * CPAD * 4);
    int* bbase  = (int*)alloc((size_t)(NBUCK + 1) * 4);
    float* ls   = (float*)alloc((size_t)BATCH * 4);
    float* l2a  = (float*)alloc((size_t)BATCH * 4);

    hipMemsetAsync(bcnt, 0, (size_t)NBUCK * CPAD * 4, stream);
    hipMemsetAsync(bfill, 0, (size_t)NBUCK * CPAD * 4, stream);

    conv_kernel<<<(U_NUM * FCT / 4 + 255) / 256, 256, 0, stream>>>(u0f, u0b, U_NUM * FCT / 4);
    conv_kernel<<<(I_NUM * FCT / 4 + 255) / 256, 256, 0, stream>>>(i0f, i0b, I_NUM * FCT / 4);

    bhist_kernel<<<(NEDGE + 255) / 256, 256, 0, stream>>>(eu, ei, bcnt);
    bscan_kernel<<<1, 256, 0, stream>>>(bcnt, bbase);
    bscatter_kernel<<<(NEDGE + 255) / 256, 256, 0, stream>>>(eu, ei, vui, viu, bbase, bfill, csr);

    agg_kernel<<<NBUCK, 256, 0, stream>>>(u0b, i0b, u1b, i1b, di, dj, bbase, csr);
    agg_kernel<<<NBUCK, 256, 0, stream>>>(u1b, i1b, u2b, i2b, di, dj, bbase, csr);
    agg_kernel<<<NBUCK, 256, 0, stream>>>(u2b, i2b, u3b, i3b, di, dj, bbase, csr);

    batch_kernel<<<(BATCH * 64) / 256, 256, 0, stream>>>(u0f, i0f, u1b, u2b, u3b,
                                                         i1b, i2b, i3b,
                                                         usr, ita, itb, out, ls, l2a);
    final_kernel<<<1, 256, 0, stream>>>(ls, l2a, out);
}

// Round 3
// 1175.584 us; speedup vs baseline: 6.5821x; 6.5821x over previous
//
#include <hip/hip_runtime.h>

#define U_NUM   100000
#define I_NUM   50000
#define FCT     64
#define NEDGE   3200000
#define BATCH   16384
#define NROWS   (U_NUM + I_NUM)      // 150000
#define TOTSLOTS (2 * NEDGE)         // 6400000

#define BSH 7                        // 128 rows per bucket
#define NBU 782                      // ceil(100000/128)
#define NBI 391                      // ceil(50000/128)
#define NBUCK (NBU + NBI)            // 1173
#define CPAD 16

__device__ __forceinline__ unsigned short f2b(float f) {
    unsigned int x = __float_as_uint(f);
    unsigned int r = (x + 0x7FFFu + ((x >> 16) & 1u)) >> 16;   // RNE
    return (unsigned short)r;
}
__device__ __forceinline__ float b2f(unsigned short u) {
    return __uint_as_float(((unsigned int)u) << 16);
}

// ---------------- fp32 -> bf16 table conversion ----------------
__global__ void conv_kernel(const float* __restrict__ in, unsigned short* __restrict__ out, int n4) {
    int t = blockIdx.x * blockDim.x + threadIdx.x;
    if (t >= n4) return;
    float4 v = *reinterpret_cast<const float4*>(in + (size_t)t * 4);
    ushort4 o;
    o.x = f2b(v.x); o.y = f2b(v.y); o.z = f2b(v.z); o.w = f2b(v.w);
    *reinterpret_cast<ushort4*>(out + (size_t)t * 4) = o;
}

// ---------------- per-row histogram ----------------
__global__ void hist_kernel(const int* __restrict__ eu, const int* __restrict__ ei,
                            int* __restrict__ cnt) {
    int t = blockIdx.x * blockDim.x + threadIdx.x;
    if (t >= NEDGE) return;
    atomicAdd(&cnt[eu[t]], 1);
    atomicAdd(&cnt[U_NUM + ei[t]], 1);
}

// ---------------- exclusive scan over NROWS (3 kernels) ----------------
__global__ void scan1_kernel(const int* __restrict__ cnt, int* __restrict__ out,
                             int* __restrict__ bsum) {
    __shared__ int s[256];
    int t = threadIdx.x;
    int base = blockIdx.x * 1024 + t * 4;
    int v[4];
#pragma unroll
    for (int k = 0; k < 4; k++) v[k] = (base + k < NROWS) ? cnt[base + k] : 0;
    int tot = v[0] + v[1] + v[2] + v[3];
    s[t] = tot;
    __syncthreads();
    for (int off = 1; off < 256; off <<= 1) {
        int x = (t >= off) ? s[t - off] : 0;
        __syncthreads();
        s[t] += x;
        __syncthreads();
    }
    int p = s[t] - tot;
#pragma unroll
    for (int k = 0; k < 4; k++) {
        if (base + k < NROWS) out[base + k] = p;
        p += v[k];
    }
    if (t == 255) bsum[blockIdx.x] = s[255];
}

__global__ void scan2_kernel(int* __restrict__ bsum, int nb) {
    __shared__ int s[256];
    int t = threadIdx.x;
    int v = (t < nb) ? bsum[t] : 0;
    s[t] = v;
    __syncthreads();
    for (int off = 1; off < 256; off <<= 1) {
        int x = (t >= off) ? s[t - off] : 0;
        __syncthreads();
        s[t] += x;
        __syncthreads();
    }
    if (t < nb) bsum[t] = s[t] - v;
}

__global__ void scan3_kernel(int* __restrict__ rowptr, const int* __restrict__ bsum) {
    int i = blockIdx.x * blockDim.x + threadIdx.x;
    if (i < NROWS) rowptr[i] += bsum[i >> 10];
    if (i == NROWS) rowptr[NROWS] = TOTSLOTS;
}

// ---------------- phase A: append edges into bucket regions (dense writes) ----------------
__global__ void bscatter_kernel(const int* __restrict__ eu, const int* __restrict__ ei,
                                const float* __restrict__ vui, const float* __restrict__ viu,
                                const int* __restrict__ rowptr, int* __restrict__ bfill,
                                int2* __restrict__ staging) {
    int t = blockIdx.x * blockDim.x + threadIdx.x;
    if (t >= NEDGE) return;
    int u = eu[t], i = ei[t];
    // user-destination edge: src = item, val = vui
    int bu = u >> BSH;
    int slot = rowptr[bu << BSH] + atomicAdd(&bfill[bu * CPAD], 1);
    staging[slot] = make_int2(((u & 127) << 17) | i, __float_as_int(vui[t]));
    // item-destination edge: src = user, val = viu
    int bi = i >> BSH;
    slot = rowptr[U_NUM + (bi << BSH)] + atomicAdd(&bfill[(NBU + bi) * CPAD], 1);
    staging[slot] = make_int2(((i & 127) << 17) | u, __float_as_int(viu[t]));
}

// ---------------- phase B: per-bucket re-scatter into exact row-CSR order ----------------
__global__ void __launch_bounds__(256) rsort_kernel(const int* __restrict__ rowptr,
                                                    const int2* __restrict__ staging,
                                                    int2* __restrict__ csr) {
    __shared__ int fillr[128];
    __shared__ int rp[129];
    int b = blockIdx.x;
    int gRowBase, rows;
    if (b < NBU) {
        gRowBase = b << BSH;
        rows = min(128, U_NUM - gRowBase);
    } else {
        int rb = (b - NBU) << BSH;
        gRowBase = U_NUM + rb;
        rows = min(128, I_NUM - rb);
    }
    for (int t = threadIdx.x; t < rows; t += 256) fillr[t] = 0;
    for (int t = threadIdx.x; t <= rows; t += 256) rp[t] = rowptr[gRowBase + t];
    __syncthreads();
    int beg = rp[0], end = rp[rows];
    for (int e = beg + threadIdx.x; e < end; e += 256) {
        int2 pk = staging[e];
        int off = pk.x >> 17;
        int src = pk.x & 0x1FFFF;
        int dst = rp[off] + atomicAdd(&fillr[off], 1);
        csr[dst] = make_int2(src, pk.y);
    }
}

// ---------------- propagation stage: wave per row, register accumulate ----------------
__global__ void __launch_bounds__(256) agg_kernel(
        const unsigned short* __restrict__ uprev, const unsigned short* __restrict__ iprev,
        unsigned short* __restrict__ unext, unsigned short* __restrict__ inext,
        const float* __restrict__ di, const float* __restrict__ dj,
        const int* __restrict__ rowptr, const int2* __restrict__ csr) {
    int wid = (blockIdx.x * 256 + threadIdx.x) >> 6;
    int lane = threadIdx.x & 63;
    if (wid >= NROWS) return;
    const unsigned short* selfP;
    const unsigned short* srcT;
    unsigned short* dst;
    float dscale;
    if (wid < U_NUM) {
        selfP = uprev + (size_t)wid * FCT;
        srcT = iprev;
        dst = unext + (size_t)wid * FCT;
        dscale = di[wid];
    } else {
        int r = wid - U_NUM;
        selfP = iprev + (size_t)r * FCT;
        srcT = uprev;
        dst = inext + (size_t)r * FCT;
        dscale = dj[r];
    }
    int beg = rowptr[wid], end = rowptr[wid + 1];
    float acc = b2f(selfP[lane]) * dscale;
    int e = beg;
    for (; e + 8 <= end; e += 8) {
        int2 p[8];
        float g[8];
#pragma unroll
        for (int k = 0; k < 8; k++) p[k] = csr[e + k];
#pragma unroll
        for (int k = 0; k < 8; k++) g[k] = b2f(srcT[(size_t)p[k].x * FCT + lane]);
#pragma unroll
        for (int k = 0; k < 8; k++) acc = fmaf(__int_as_float(p[k].y), g[k], acc);
    }
    for (; e < end; ++e) {
        int2 p = csr[e];
        acc = fmaf(__int_as_float(p.y), b2f(srcT[(size_t)p.x * FCT + lane]), acc);
    }
    dst[lane] = f2b(acc);
}

// ---------------- BPR head ----------------
__global__ void __launch_bounds__(256) batch_kernel(
        const float* __restrict__ u0f, const float* __restrict__ i0f,
        const unsigned short* __restrict__ u1, const unsigned short* __restrict__ u2,
        const unsigned short* __restrict__ u3,
        const unsigned short* __restrict__ i1, const unsigned short* __restrict__ i2,
        const unsigned short* __restrict__ i3,
        const int* __restrict__ user, const int* __restrict__ ita, const int* __restrict__ itb,
        float* __restrict__ out, float* __restrict__ ls, float* __restrict__ l2a) {
    int wid = (blockIdx.x * 256 + threadIdx.x) >> 6;
    int lane = threadIdx.x & 63;
    if (wid >= BATCH) return;
    size_t uo = (size_t)user[wid] * FCT + lane;
    size_t ao = (size_t)ita[wid] * FCT + lane;
    size_t bo = (size_t)itb[wid] * FCT + lane;

    float pi, pj, l2;
    {
        float ue = u0f[uo], ie = i0f[ao], je = i0f[bo];
        pi = ue * ie; pj = ue * je; l2 = ue * ue + ie * ie + je * je;
    }
    const unsigned short* Ut[3] = {u1, u2, u3};
    const unsigned short* It[3] = {i1, i2, i3};
#pragma unroll
    for (int l = 0; l < 3; l++) {
        float ue = b2f(Ut[l][uo]), ie = b2f(It[l][ao]), je = b2f(It[l][bo]);
        pi += ue * ie;
        pj += ue * je;
        l2 += ue * ue + ie * ie + je * je;
    }
#pragma unroll
    for (int off = 32; off; off >>= 1) {
        pi += __shfl_xor(pi, off);
        pj += __shfl_xor(pj, off);
        l2 += __shfl_xor(l2, off);
    }
    if (lane == 0) {
        out[wid] = pi;
        out[BATCH + wid] = pj;
        float x = pi - pj;
        ls[wid] = fminf(x, 0.0f) - log1pf(expf(-fabsf(x)));
        l2a[wid] = 0.01f * l2;
    }
}

__global__ void final_kernel(const float* __restrict__ ls, const float* __restrict__ l2a,
                             float* __restrict__ out) {
    __shared__ float s1[256], s2[256];
    int t = threadIdx.x;
    float a = 0.f, b = 0.f;
    for (int i = t; i < BATCH; i += 256) {
        a += ls[i];
        b += l2a[i];
    }
    s1[t] = a;
    s2[t] = b;
    __syncthreads();
    for (int off = 128; off; off >>= 1) {
        if (t < off) {
            s1[t] += s1[t + off];
            s2[t] += s2[t + off];
        }
        __syncthreads();
    }
    if (t == 0) {
        float loss2 = -s1[0] / (float)BATCH;
        float l2m = s2[0] / (float)BATCH;
        out[2 * BATCH] = loss2 + l2m;
        out[2 * BATCH + 1] = loss2;
    }
}

// ---------------- launch ----------------
extern "C" void kernel_launch(void* const* d_in, const int* in_sizes, int n_in,
                              void* d_out, int out_size, void* d_ws, size_t ws_size,
                              hipStream_t stream) {
    const float* u0f = (const float*)d_in[0];
    const float* i0f = (const float*)d_in[1];
    const float* di  = (const float*)d_in[2];
    const float* dj  = (const float*)d_in[3];
    const float* vui = (const float*)d_in[4];
    const float* viu = (const float*)d_in[5];
    const int*   eu  = (const int*)d_in[6];
    const int*   ei  = (const int*)d_in[7];
    const int*   usr = (const int*)d_in[8];
    const int*   ita = (const int*)d_in[9];
    const int*   itb = (const int*)d_in[10];
    float* out = (float*)d_out;

    char* p = (char*)d_ws;
    auto alloc = [&](size_t bytes) -> char* {
        char* r = p;
        p += (bytes + 255) & ~(size_t)255;
        return r;
    };
    unsigned short* u0b = (unsigned short*)alloc((size_t)U_NUM * FCT * 2);
    unsigned short* u1b = (unsigned short*)alloc((size_t)U_NUM * FCT * 2);
    unsigned short* i0b = (unsigned short*)alloc((size_t)I_NUM * FCT * 2);
    unsigned short* i1b = (unsigned short*)alloc((size_t)I_NUM * FCT * 2);
    int2* csr     = (int2*)alloc((size_t)TOTSLOTS * 8);
    int2* staging = (int2*)alloc((size_t)TOTSLOTS * 8);
    int* rowptr = (int*)alloc((size_t)(NROWS + 1) * 4);
    int* cnt    = (int*)alloc((size_t)NROWS * 4);
    int* bsum   = (int*)alloc(256 * 4);
    int* bfill  = (int*)alloc((size_t)NBUCK * CPAD * 4);
    float* ls   = (float*)alloc((size_t)BATCH * 4);
    float* l2a  = (float*)alloc((size_t)BATCH * 4);
    // overlay levels 2,3 on the staging buffer (staging dead after rsort; these
    // tables are written by agg2/agg3 which run strictly later on the stream)
    unsigned short* u2b = (unsigned short*)staging;                       // 12.8 MB
    unsigned short* u3b = u2b + (size_t)U_NUM * FCT;                      // 12.8 MB
    unsigned short* i2b = u3b + (size_t)U_NUM * FCT;                      // 6.4 MB
    unsigned short* i3b = i2b + (size_t)I_NUM * FCT;                      // 6.4 MB (38.4 <= 51.2 MB)

    hipMemsetAsync(cnt, 0, (size_t)NROWS * 4, stream);
    hipMemsetAsync(bfill, 0, (size_t)NBUCK * CPAD * 4, stream);

    conv_kernel<<<(U_NUM * FCT / 4 + 255) / 256, 256, 0, stream>>>(u0f, u0b, U_NUM * FCT / 4);
    conv_kernel<<<(I_NUM * FCT / 4 + 255) / 256, 256, 0, stream>>>(i0f, i0b, I_NUM * FCT / 4);

    hist_kernel<<<(NEDGE + 255) / 256, 256, 0, stream>>>(eu, ei, cnt);
    int nb = (NROWS + 1023) / 1024;
    scan1_kernel<<<nb, 256, 0, stream>>>(cnt, rowptr, bsum);
    scan2_kernel<<<1, 256, 0, stream>>>(bsum, nb);
    scan3_kernel<<<(NROWS + 1 + 255) / 256, 256, 0, stream>>>(rowptr, bsum);

    bscatter_kernel<<<(NEDGE + 255) / 256, 256, 0, stream>>>(eu, ei, vui, viu, rowptr, bfill, staging);
    rsort_kernel<<<NBUCK, 256, 0, stream>>>(rowptr, staging, csr);

    int aggGrid = (NROWS * 64) / 256 + 1;
    agg_kernel<<<aggGrid, 256, 0, stream>>>(u0b, i0b, u1b, i1b, di, dj, rowptr, csr);
    agg_kernel<<<aggGrid, 256, 0, stream>>>(u1b, i1b, u2b, i2b, di, dj, rowptr, csr);
    agg_kernel<<<aggGrid, 256, 0, stream>>>(u2b, i2b, u3b, i3b, di, dj, rowptr, csr);

    batch_kernel<<<(BATCH * 64) / 256, 256, 0, stream>>>(u0f, i0f, u1b, u2b, u3b,
                                                         i1b, i2b, i3b,
                                                         usr, ita, itb, out, ls, l2a);
    final_kernel<<<1, 256, 0, stream>>>(ls, l2a, out);
}